// Round 4
// baseline (52612.506 us; speedup 1.0000x reference)
//
#include <hip/hip_runtime.h>

// B=2048, T=128, N=64, H=128
// inputs: 0 X(2048,128,64) 1 W_attn1(128,384) 2 b_attn1(128) 3 w_attn2(128)
//         4 b_attn2(1)[unused] 5 W_ih(512,64) 6 W_hh(512,128) 7 b_ih(512) 8 b_hh(512)
// output: (2048,128,128) f32
// ws (floats): Wt[128][128] @0 | W1T[256][128] @16384 | WcT[192][512] @49152 | prex @147456

typedef float f32x4 __attribute__((ext_vector_type(4)));

#define LOG2E 1.44269504088896340736f
__device__ __forceinline__ float rcpf(float x){ return __builtin_amdgcn_rcpf(x); }
__device__ __forceinline__ float fast_exp(float x){ return __builtin_exp2f(x * LOG2E); }
__device__ __forceinline__ float fast_tanh(float x){
  float e = __builtin_exp2f(x * (2.0f * LOG2E));
  return 1.0f - 2.0f * rcpf(e + 1.0f);
}
__device__ __forceinline__ float fast_sig(float x){
  float e = __builtin_exp2f(x * (-LOG2E));
  return rcpf(1.0f + e);
}

// ---- packs ----
__global__ __launch_bounds__(256) void k0_wt(const float* __restrict__ Wat, float* __restrict__ Wt){
  int idx = blockIdx.x*256 + threadIdx.x;   // 16384
  int t = idx >> 7, k = idx & 127;
  Wt[idx] = Wat[k*384 + 256 + t];
}
__global__ __launch_bounds__(256) void k0_w1t(const float* __restrict__ Wat, float* __restrict__ W1T){
  int idx = blockIdx.x*256 + threadIdx.x;   // 32768
  int c = idx >> 7, k = idx & 127;
  W1T[idx] = Wat[k*384 + c];                // [W1h | W1s] columns
}
__global__ __launch_bounds__(256) void k0_wct(const float* __restrict__ Wih, const float* __restrict__ Whh,
                                              float* __restrict__ WcT){
  int idx = blockIdx.x*256 + threadIdx.x;   // 98304
  int c = idx >> 9, g = idx & 511;
  WcT[idx] = (c < 64) ? Wih[g*64 + c] : Whh[g*128 + (c-64)];
}

// ---- k1: prex[b][n][k] = sum_t X[b][t][n]*W1x[k][t] + b1[k] ----
__global__ __launch_bounds__(256) void k1_prex(const float* __restrict__ X,
                                               const float* __restrict__ Wt,
                                               const float* __restrict__ b1,
                                               float* __restrict__ prex){
  __shared__ float Xs[128][64];
  const int tid = threadIdx.x;
  const long b = blockIdx.x;
  {
    const float4* X4 = (const float4*)(X + b*8192);
    float4* Xs4 = (float4*)&Xs[0][0];
    #pragma unroll
    for (int i=0;i<8;i++) Xs4[tid + i*256] = X4[tid + i*256];
  }
  __syncthreads();
  const int nq = tid >> 4, kq = tid & 15;
  float acc[4][8];
  #pragma unroll
  for (int n=0;n<4;n++)
    #pragma unroll
    for (int k=0;k<8;k++) acc[n][k]=0.f;
  #pragma unroll 4
  for (int t=0;t<128;t++){
    float4 w0 = *(const float4*)(Wt + t*128 + kq*8);
    float4 w1 = *(const float4*)(Wt + t*128 + kq*8 + 4);
    float4 xv = *(const float4*)&Xs[t][nq*4];
    float wv[8] = {w0.x,w0.y,w0.z,w0.w,w1.x,w1.y,w1.z,w1.w};
    float xa[4] = {xv.x,xv.y,xv.z,xv.w};
    #pragma unroll
    for (int n=0;n<4;n++)
      #pragma unroll
      for (int k=0;k<8;k++) acc[n][k] = fmaf(xa[n], wv[k], acc[n][k]);
  }
  float4 bv0 = *(const float4*)(b1 + kq*8);
  float4 bv1 = *(const float4*)(b1 + kq*8 + 4);
  #pragma unroll
  for (int n=0;n<4;n++){
    float* dst = prex + (b*64 + nq*4 + n)*128 + kq*8;
    *(float4*)(dst)   = make_float4(acc[n][0]+bv0.x, acc[n][1]+bv0.y,
                                    acc[n][2]+bv0.z, acc[n][3]+bv0.w);
    *(float4*)(dst+4) = make_float4(acc[n][4]+bv1.x, acc[n][5]+bv1.y,
                                    acc[n][6]+bv1.z, acc[n][7]+bv1.w);
  }
}

// ---- k2: persistent recurrence. 256 blocks x 1024 thr, 8 batches/block ----
// Weights stream from L2 (nt-loads keep prex/X from evicting them).
// All global accesses lane-minor coalesced; LDS broadcasts for activations.
__global__ __launch_bounds__(1024)
__attribute__((amdgpu_waves_per_eu(4, 4)))
void k2_lstm(const float* __restrict__ X,
             const float* __restrict__ W1T,
             const float* __restrict__ WcT,
             const float* __restrict__ w2,
             const float* __restrict__ b1,
             const float* __restrict__ bih,
             const float* __restrict__ bhh,
             const float* __restrict__ prex,
             float* __restrict__ out)
{
  const int tid = threadIdx.x;
  const long b0 = (long)blockIdx.x * 8;

  __shared__ union {
    float aap[8][8][128];   // P1 partials  [c-slice][b][k]     32 KB
    float ep[512][36];      // P2 partials  [b*64+n][k4]        73.7 KB
    float gp[4][8][516];    // P4 partials  [c-slice][b][g]     66 KB
  } u;
  __shared__ float actT[192][12];  // rows: [0,64) = x_tilde[n][b], [64,192) = h[j][b]
  __shared__ float cstT[128][12];  // c-state [j][b]
  __shared__ float aa[8][132];     // attn pre-act (h,c part + b1)
  __shared__ float b1s[128];

  for (int i = tid; i < 192*12; i += 1024) (&actT[0][0])[i] = 0.f;
  for (int i = tid; i < 128*12; i += 1024) (&cstT[0][0])[i] = 0.f;
  if (tid < 128) b1s[tid] = b1[tid];
  __syncthreads();

  // ---- role indices
  const int p1_cs = tid >> 7, p1_k = tid & 127;         // c-slice (32 c's), k
  const float* p1_w = W1T + (p1_cs*32)*128 + p1_k;
  const f32x4* p1_a = (p1_cs < 4) ? (const f32x4*)&actT[64 + p1_cs*32][0]
                                  : (const f32x4*)&cstT[(p1_cs-4)*32][0];

  const int p2_k4 = tid & 31, p2_n0 = tid >> 5;         // k-quad, n-base
  const f32x4 p2_wv = *(const f32x4*)(w2 + p2_k4*4);
  const f32x4* p2_px = (const f32x4*)prex + b0*2048 + tid;

  const int p4_ch = tid >> 8, p4_bh = (tid>>7)&1, p4_g4 = tid & 127;  // c-slice(48), b-half, g-quad
  const f32x4* p4_w = (const f32x4*)WcT + (p4_ch*48)*128 + p4_g4;

  const int o_b = tid >> 7, o_j = tid & 127;
  const float bl0 = bih[o_j]       + bhh[o_j];
  const float bl1 = bih[o_j + 128] + bhh[o_j + 128];
  const float bl2 = bih[o_j + 256] + bhh[o_j + 256];
  const float bl3 = bih[o_j + 384] + bhh[o_j + 384];

  for (int t = 0; t < 128; ++t) {
    // ---------- P1: aap[cs][b][k] = sum_{c in slice} hc[b][c] * W1[k][c]
    {
      float acc[8] = {0,0,0,0,0,0,0,0};
      #pragma unroll
      for (int c = 0; c < 32; c += 2) {
        float w0 = p1_w[(c  )*128];
        float w1 = p1_w[(c+1)*128];
        f32x4 a00 = p1_a[c*3],     a01 = p1_a[c*3 + 1];
        f32x4 a10 = p1_a[c*3 + 3], a11 = p1_a[c*3 + 4];
        acc[0]=fmaf(w0,a00.x,acc[0]); acc[1]=fmaf(w0,a00.y,acc[1]);
        acc[2]=fmaf(w0,a00.z,acc[2]); acc[3]=fmaf(w0,a00.w,acc[3]);
        acc[4]=fmaf(w0,a01.x,acc[4]); acc[5]=fmaf(w0,a01.y,acc[5]);
        acc[6]=fmaf(w0,a01.z,acc[6]); acc[7]=fmaf(w0,a01.w,acc[7]);
        acc[0]=fmaf(w1,a10.x,acc[0]); acc[1]=fmaf(w1,a10.y,acc[1]);
        acc[2]=fmaf(w1,a10.z,acc[2]); acc[3]=fmaf(w1,a10.w,acc[3]);
        acc[4]=fmaf(w1,a11.x,acc[4]); acc[5]=fmaf(w1,a11.y,acc[5]);
        acc[6]=fmaf(w1,a11.z,acc[6]); acc[7]=fmaf(w1,a11.w,acc[7]);
      }
      #pragma unroll
      for (int b = 0; b < 8; ++b) u.aap[p1_cs][b][p1_k] = acc[b];
    }
    __syncthreads();

    // ---------- P1b: aa[b][k] = b1[k] + sum_cs aap
    {
      float s = b1s[p1_k];
      #pragma unroll
      for (int cs = 0; cs < 8; ++cs) s += u.aap[cs][o_b][p1_k];
      aa[o_b][p1_k] = s;
    }
    __syncthreads();

    // ---------- P2: ep[(b,n)][k4] = sum_{4k} tanh(prex+aa)*w2
    #pragma unroll
    for (int b = 0; b < 8; ++b) {
      f32x4 av = *(const f32x4*)&aa[b][p2_k4*4];
      f32x4 pA = __builtin_nontemporal_load(p2_px + (2*b  )*1024);
      f32x4 pB = __builtin_nontemporal_load(p2_px + (2*b+1)*1024);
      float sA = fmaf(fast_tanh(pA.x+av.x), p2_wv.x,
                 fmaf(fast_tanh(pA.y+av.y), p2_wv.y,
                 fmaf(fast_tanh(pA.z+av.z), p2_wv.z,
                      fast_tanh(pA.w+av.w) * p2_wv.w)));
      float sB = fmaf(fast_tanh(pB.x+av.x), p2_wv.x,
                 fmaf(fast_tanh(pB.y+av.y), p2_wv.y,
                 fmaf(fast_tanh(pB.z+av.z), p2_wv.z,
                      fast_tanh(pB.w+av.w) * p2_wv.w)));
      u.ep[b*64 + p2_n0     ][p2_k4] = sA;
      u.ep[b*64 + 32 + p2_n0][p2_k4] = sB;
    }
    __syncthreads();

    // ---------- P3: reduce k4, softmax over n, x_tilde -> actT[n][b]
    if (tid < 512) {
      int b = tid >> 6, n = tid & 63;
      const f32x4* er = (const f32x4*)&u.ep[b*64 + n][0];
      f32x4 e4 = er[0];
      #pragma unroll
      for (int j = 1; j < 8; ++j) e4 += er[j];
      float e = (e4.x + e4.y) + (e4.z + e4.w);
      float mx = e;
      #pragma unroll
      for (int m=32;m>=1;m>>=1) mx = fmaxf(mx, __shfl_xor(mx,m,64));
      float p = fast_exp(e - mx);
      float sm = p;
      #pragma unroll
      for (int m=32;m>=1;m>>=1) sm += __shfl_xor(sm,m,64);
      float xv = __builtin_nontemporal_load(X + (b0+b)*8192 + (long)t*64 + n);
      actT[n][b] = p * rcpf(sm) * xv;
    }
    __syncthreads();

    // ---------- P4: gate partials gp[ch][b][g] over act=[xt|h]
    {
      float pc[4][4];
      #pragma unroll
      for (int g=0; g<4; ++g)
        #pragma unroll
        for (int b=0; b<4; ++b) pc[g][b] = 0.f;
      const int cb = p4_ch*48;
      #pragma unroll
      for (int c = 0; c < 48; c += 2) {
        f32x4 w0 = p4_w[(c  )*128];
        f32x4 w1 = p4_w[(c+1)*128];
        f32x4 a0 = *(const f32x4*)&actT[cb + c    ][p4_bh*4];
        f32x4 a1 = *(const f32x4*)&actT[cb + c + 1][p4_bh*4];
        pc[0][0]=fmaf(w0.x,a0.x,pc[0][0]); pc[1][0]=fmaf(w0.y,a0.x,pc[1][0]);
        pc[2][0]=fmaf(w0.z,a0.x,pc[2][0]); pc[3][0]=fmaf(w0.w,a0.x,pc[3][0]);
        pc[0][1]=fmaf(w0.x,a0.y,pc[0][1]); pc[1][1]=fmaf(w0.y,a0.y,pc[1][1]);
        pc[2][1]=fmaf(w0.z,a0.y,pc[2][1]); pc[3][1]=fmaf(w0.w,a0.y,pc[3][1]);
        pc[0][2]=fmaf(w0.x,a0.z,pc[0][2]); pc[1][2]=fmaf(w0.y,a0.z,pc[1][2]);
        pc[2][2]=fmaf(w0.z,a0.z,pc[2][2]); pc[3][2]=fmaf(w0.w,a0.z,pc[3][2]);
        pc[0][3]=fmaf(w0.x,a0.w,pc[0][3]); pc[1][3]=fmaf(w0.y,a0.w,pc[1][3]);
        pc[2][3]=fmaf(w0.z,a0.w,pc[2][3]); pc[3][3]=fmaf(w0.w,a0.w,pc[3][3]);
        pc[0][0]=fmaf(w1.x,a1.x,pc[0][0]); pc[1][0]=fmaf(w1.y,a1.x,pc[1][0]);
        pc[2][0]=fmaf(w1.z,a1.x,pc[2][0]); pc[3][0]=fmaf(w1.w,a1.x,pc[3][0]);
        pc[0][1]=fmaf(w1.x,a1.y,pc[0][1]); pc[1][1]=fmaf(w1.y,a1.y,pc[1][1]);
        pc[2][1]=fmaf(w1.z,a1.y,pc[2][1]); pc[3][1]=fmaf(w1.w,a1.y,pc[3][1]);
        pc[0][2]=fmaf(w1.x,a1.z,pc[0][2]); pc[1][2]=fmaf(w1.y,a1.z,pc[1][2]);
        pc[2][2]=fmaf(w1.z,a1.z,pc[2][2]); pc[3][2]=fmaf(w1.w,a1.z,pc[3][2]);
        pc[0][3]=fmaf(w1.x,a1.w,pc[0][3]); pc[1][3]=fmaf(w1.y,a1.w,pc[1][3]);
        pc[2][3]=fmaf(w1.z,a1.w,pc[2][3]); pc[3][3]=fmaf(w1.w,a1.w,pc[3][3]);
      }
      #pragma unroll
      for (int bb = 0; bb < 4; ++bb) {
        f32x4 v; v.x = pc[0][bb]; v.y = pc[1][bb]; v.z = pc[2][bb]; v.w = pc[3][bb];
        *(f32x4*)&u.gp[p4_ch][p4_bh*4 + bb][p4_g4*4] = v;
      }
    }
    __syncthreads();

    // ---------- P4b: sum slices, pointwise LSTM, write state + out
    {
      float s0 = bl0, s1 = bl1, s2 = bl2, s3 = bl3;
      #pragma unroll
      for (int ch = 0; ch < 4; ++ch) {
        s0 += u.gp[ch][o_b][o_j];
        s1 += u.gp[ch][o_b][o_j + 128];
        s2 += u.gp[ch][o_b][o_j + 256];
        s3 += u.gp[ch][o_b][o_j + 384];
      }
      float ig = fast_sig(s0), fg = fast_sig(s1);
      float gg = fast_tanh(s2), og = fast_sig(s3);
      float cn = fmaf(fg, cstT[o_j][o_b], ig*gg);
      float hn = og * fast_tanh(cn);
      cstT[o_j][o_b] = cn;
      actT[64 + o_j][o_b] = hn;
      __builtin_nontemporal_store(hn, out + (b0+o_b)*16384 + (long)t*128 + o_j);
    }
    __syncthreads();
  }
}

extern "C" void kernel_launch(void* const* d_in, const int* in_sizes, int n_in,
                              void* d_out, int out_size, void* d_ws, size_t ws_size,
                              hipStream_t stream) {
  const float* X   = (const float*)d_in[0];
  const float* Wat = (const float*)d_in[1];
  const float* b1  = (const float*)d_in[2];
  const float* w2  = (const float*)d_in[3];
  const float* Wih = (const float*)d_in[5];
  const float* Whh = (const float*)d_in[6];
  const float* bih = (const float*)d_in[7];
  const float* bhh = (const float*)d_in[8];
  float* out  = (float*)d_out;
  float* Wt   = (float*)d_ws;            // 16384
  float* W1T  = Wt + 16384;              // 32768
  float* WcT  = W1T + 32768;             // 98304
  float* prex = WcT + 98304;             // 16777216

  k0_wt  <<<64,  256, 0, stream>>>(Wat, Wt);
  k0_w1t <<<128, 256, 0, stream>>>(Wat, W1T);
  k0_wct <<<384, 256, 0, stream>>>(Wih, Whh, WcT);
  k1_prex<<<2048,256, 0, stream>>>(X, Wt, b1, prex);
  k2_lstm<<<256,1024, 0, stream>>>(X, W1T, WcT, w2, b1, bih, bhh, prex, out);
}

// Round 5
// 3116.597 us; speedup vs baseline: 16.8814x; 16.8814x over previous
//
#include <hip/hip_runtime.h>

// B=2048, T=128, N=64, H=128
// inputs: 0 X(2048,128,64) 1 W_attn1(128,384) 2 b_attn1(128) 3 w_attn2(128)
//         4 b_attn2(1)[unused] 5 W_ih(512,64) 6 W_hh(512,128) 7 b_ih(512) 8 b_hh(512)
// output: (2048,128,128) f32
// ws (floats): Wt[128][128] @0 | W1T[256][128] @16384 | WcT[192][512] @49152 | prex @147456
//
// k2 design (R5): 512 blocks x 512 threads, 4 batches/block, 1 block/CU (LDS-capped).
// prex slice (128 KB) loaded to LDS ONCE, XOR-swizzled quads -> conflict-free reads.
// Per-step global traffic = shared weights only (L2-hot: 512 KB working set/XCD).
// All per-thread accumulators <= 4 floats -> no spill even at VGPR=64.

typedef float f32x4 __attribute__((ext_vector_type(4)));

#define LOG2E 1.44269504088896340736f
__device__ __forceinline__ float rcpf(float x){ return __builtin_amdgcn_rcpf(x); }
__device__ __forceinline__ float fast_exp(float x){ return __builtin_exp2f(x * LOG2E); }
__device__ __forceinline__ float fast_tanh(float x){
  float e = __builtin_exp2f(x * (2.0f * LOG2E));
  return 1.0f - 2.0f * rcpf(e + 1.0f);
}
__device__ __forceinline__ float fast_sig(float x){
  float e = __builtin_exp2f(x * (-LOG2E));
  return rcpf(1.0f + e);
}

// ---- packs ----
__global__ __launch_bounds__(256) void k0_wt(const float* __restrict__ Wat, float* __restrict__ Wt){
  int idx = blockIdx.x*256 + threadIdx.x;   // 16384
  int t = idx >> 7, k = idx & 127;
  Wt[idx] = Wat[k*384 + 256 + t];
}
__global__ __launch_bounds__(256) void k0_w1t(const float* __restrict__ Wat, float* __restrict__ W1T){
  int idx = blockIdx.x*256 + threadIdx.x;   // 32768
  int c = idx >> 7, k = idx & 127;
  W1T[idx] = Wat[k*384 + c];                // [W1h | W1s] columns (c<128: h, else c-state)
}
__global__ __launch_bounds__(256) void k0_wct(const float* __restrict__ Wih, const float* __restrict__ Whh,
                                              float* __restrict__ WcT){
  int idx = blockIdx.x*256 + threadIdx.x;   // 98304
  int c = idx >> 9, g = idx & 511;
  WcT[idx] = (c < 64) ? Wih[g*64 + c] : Whh[g*128 + (c-64)];
}

// ---- k1: prex[b][n][k] = sum_t X[b][t][n]*W1x[k][t] + b1[k] ----
__global__ __launch_bounds__(256) void k1_prex(const float* __restrict__ X,
                                               const float* __restrict__ Wt,
                                               const float* __restrict__ b1,
                                               float* __restrict__ prex){
  __shared__ float Xs[128][64];
  const int tid = threadIdx.x;
  const long b = blockIdx.x;
  {
    const float4* X4 = (const float4*)(X + b*8192);
    float4* Xs4 = (float4*)&Xs[0][0];
    #pragma unroll
    for (int i=0;i<8;i++) Xs4[tid + i*256] = X4[tid + i*256];
  }
  __syncthreads();
  const int nq = tid >> 4, kq = tid & 15;
  float acc[4][8];
  #pragma unroll
  for (int n=0;n<4;n++)
    #pragma unroll
    for (int k=0;k<8;k++) acc[n][k]=0.f;
  #pragma unroll 4
  for (int t=0;t<128;t++){
    float4 w0 = *(const float4*)(Wt + t*128 + kq*8);
    float4 w1 = *(const float4*)(Wt + t*128 + kq*8 + 4);
    float4 xv = *(const float4*)&Xs[t][nq*4];
    float wv[8] = {w0.x,w0.y,w0.z,w0.w,w1.x,w1.y,w1.z,w1.w};
    float xa[4] = {xv.x,xv.y,xv.z,xv.w};
    #pragma unroll
    for (int n=0;n<4;n++)
      #pragma unroll
      for (int k=0;k<8;k++) acc[n][k] = fmaf(xa[n], wv[k], acc[n][k]);
  }
  float4 bv0 = *(const float4*)(b1 + kq*8);
  float4 bv1 = *(const float4*)(b1 + kq*8 + 4);
  #pragma unroll
  for (int n=0;n<4;n++){
    float* dst = prex + (b*64 + nq*4 + n)*128 + kq*8;
    *(float4*)(dst)   = make_float4(acc[n][0]+bv0.x, acc[n][1]+bv0.y,
                                    acc[n][2]+bv0.z, acc[n][3]+bv0.w);
    *(float4*)(dst+4) = make_float4(acc[n][4]+bv1.x, acc[n][5]+bv1.y,
                                    acc[n][6]+bv1.z, acc[n][7]+bv1.w);
  }
}

// ---- k2 ----
__global__ __launch_bounds__(512, 2)
void k2_lstm(const float* __restrict__ X,
             const float* __restrict__ W1T,
             const float* __restrict__ WcT,
             const float* __restrict__ w2,
             const float* __restrict__ bih,
             const float* __restrict__ bhh,
             const float* __restrict__ prex,
             float* __restrict__ out)
{
  const int tid = threadIdx.x;
  const long b0 = (long)blockIdx.x * 4;

  __shared__ float px[4][64][128];   // prex slice, XOR-swizzled quads   128 KB
  __shared__ union {
    float aap[4][4][128];            // P1 partials [cs][b][k]           8 KB
    float gp[4][512];                // P4 gate sums [b][g]
    float ep[4][64][2];              // P2 partials [b][n][kh]
  } u;
  __shared__ float aa[4][128];       // a_h + a_c
  __shared__ float xt[4][64];        // alpha * x_t
  __shared__ float hsd[4][128];      // h state
  __shared__ float csd[4][128];      // c state
  __shared__ float w2s[128];

  // ---- init
  if (tid < 128) w2s[tid] = w2[tid];
  { int b = tid >> 7, j = tid & 127; hsd[b][j] = 0.f; csd[b][j] = 0.f; }

  // ---- load prex slice -> LDS, swizzled: quad (b,n,kq) stored at kq^(n&7)
  {
    const f32x4* pg = (const f32x4*)prex + b0*2048;
    f32x4* pl = (f32x4*)&px[0][0][0];
    #pragma unroll
    for (int i = 0; i < 16; ++i) {
      int lin = tid + i*512;                 // 0..8191 = b*2048 + n*32 + kq
      int n  = (lin >> 5) & 63, kq = lin & 31;
      pl[(lin & ~31) | (kq ^ (n & 7))] = pg[lin];
    }
  }
  __syncthreads();

  // ---- role indices
  const int p1_cs = tid >> 7, p1_k = tid & 127;
  const float* p1_w = W1T + (p1_cs*64)*128 + p1_k;
  const float* p1_hc = (p1_cs < 2) ? &hsd[0][0] : &csd[0][0];
  const int p1_off = (p1_cs & 1) * 64;

  const int p2_n = tid & 63, p2_kh = (tid >> 6) & 1, p2_b = tid >> 7;
  const f32x4* p2_row = (const f32x4*)&px[p2_b][p2_n][0];

  const int p4_g = tid;
  const float* p4_w = WcT + p4_g;

  const int o_b = tid >> 7, o_j = tid & 127;
  const float bl0 = bih[o_j]       + bhh[o_j];
  const float bl1 = bih[o_j + 128] + bhh[o_j + 128];
  const float bl2 = bih[o_j + 256] + bhh[o_j + 256];
  const float bl3 = bih[o_j + 384] + bhh[o_j + 384];

  for (int t = 0; t < 128; ++t) {
    // ---------- P1: aap[cs][b][k] = sum_{c in 64-slice} hc[b][c] * W1[c][k]
    {
      float a0=0.f, a1=0.f, a2=0.f, a3=0.f;
      #pragma unroll 2
      for (int cc = 0; cc < 64; cc += 4) {
        float w0 = p1_w[(cc+0)*128];
        float w1 = p1_w[(cc+1)*128];
        float w2_ = p1_w[(cc+2)*128];
        float w3 = p1_w[(cc+3)*128];
        f32x4 h0 = *(const f32x4*)(p1_hc + 0*128 + p1_off + cc);
        f32x4 h1 = *(const f32x4*)(p1_hc + 1*128 + p1_off + cc);
        f32x4 h2 = *(const f32x4*)(p1_hc + 2*128 + p1_off + cc);
        f32x4 h3 = *(const f32x4*)(p1_hc + 3*128 + p1_off + cc);
        a0 = fmaf(h0.x,w0, fmaf(h0.y,w1, fmaf(h0.z,w2_, fmaf(h0.w,w3, a0))));
        a1 = fmaf(h1.x,w0, fmaf(h1.y,w1, fmaf(h1.z,w2_, fmaf(h1.w,w3, a1))));
        a2 = fmaf(h2.x,w0, fmaf(h2.y,w1, fmaf(h2.z,w2_, fmaf(h2.w,w3, a2))));
        a3 = fmaf(h3.x,w0, fmaf(h3.y,w1, fmaf(h3.z,w2_, fmaf(h3.w,w3, a3))));
      }
      u.aap[p1_cs][0][p1_k] = a0;
      u.aap[p1_cs][1][p1_k] = a1;
      u.aap[p1_cs][2][p1_k] = a2;
      u.aap[p1_cs][3][p1_k] = a3;
    }
    __syncthreads();

    // ---------- P1b: aa[b][k] = sum_cs aap  (b1 already inside prex!)
    {
      float s = u.aap[0][o_b][o_j] + u.aap[1][o_b][o_j]
              + u.aap[2][o_b][o_j] + u.aap[3][o_b][o_j];
      aa[o_b][o_j] = s;
    }
    __syncthreads();

    // ---------- P2: ep[b][n][kh] = sum_{64k} tanh(px+aa)*w2
    {
      float e = 0.f;
      #pragma unroll 4
      for (int i = 0; i < 16; ++i) {
        int kq = p2_kh*16 + i;
        f32x4 p = p2_row[kq ^ (p2_n & 7)];
        f32x4 a = *(const f32x4*)&aa[p2_b][kq*4];
        f32x4 w = *(const f32x4*)&w2s[kq*4];
        e = fmaf(fast_tanh(p.x+a.x), w.x,
            fmaf(fast_tanh(p.y+a.y), w.y,
            fmaf(fast_tanh(p.z+a.z), w.z,
            fmaf(fast_tanh(p.w+a.w), w.w, e))));
      }
      u.ep[p2_b][p2_n][p2_kh] = e;
    }
    __syncthreads();

    // ---------- P3: softmax over n (wave = one b), x_tilde
    if (tid < 256) {
      int b = tid >> 6, n = tid & 63;
      float e = u.ep[b][n][0] + u.ep[b][n][1];
      float mx = e;
      #pragma unroll
      for (int m=32;m>=1;m>>=1) mx = fmaxf(mx, __shfl_xor(mx,m,64));
      float p = fast_exp(e - mx);
      float sm = p;
      #pragma unroll
      for (int m=32;m>=1;m>>=1) sm += __shfl_xor(sm,m,64);
      xt[b][n] = p * rcpf(sm) * X[(b0+b)*8192 + (long)t*64 + n];
    }
    __syncthreads();

    // ---------- P4: gates[b][g] = xt.Wih + h.Whh  (thread = one g, 4 b's)
    {
      float g0=0.f, g1=0.f, g2=0.f, g3=0.f;
      #pragma unroll 2
      for (int c = 0; c < 64; c += 4) {       // x-part
        float w0 = p4_w[(c+0)*512];
        float w1 = p4_w[(c+1)*512];
        float w2_ = p4_w[(c+2)*512];
        float w3 = p4_w[(c+3)*512];
        f32x4 a0 = *(const f32x4*)&xt[0][c];
        f32x4 a1 = *(const f32x4*)&xt[1][c];
        f32x4 a2 = *(const f32x4*)&xt[2][c];
        f32x4 a3 = *(const f32x4*)&xt[3][c];
        g0 = fmaf(a0.x,w0, fmaf(a0.y,w1, fmaf(a0.z,w2_, fmaf(a0.w,w3, g0))));
        g1 = fmaf(a1.x,w0, fmaf(a1.y,w1, fmaf(a1.z,w2_, fmaf(a1.w,w3, g1))));
        g2 = fmaf(a2.x,w0, fmaf(a2.y,w1, fmaf(a2.z,w2_, fmaf(a2.w,w3, g2))));
        g3 = fmaf(a3.x,w0, fmaf(a3.y,w1, fmaf(a3.z,w2_, fmaf(a3.w,w3, g3))));
      }
      #pragma unroll 2
      for (int c = 0; c < 128; c += 4) {      // h-part
        float w0 = p4_w[(64+c+0)*512];
        float w1 = p4_w[(64+c+1)*512];
        float w2_ = p4_w[(64+c+2)*512];
        float w3 = p4_w[(64+c+3)*512];
        f32x4 a0 = *(const f32x4*)&hsd[0][c];
        f32x4 a1 = *(const f32x4*)&hsd[1][c];
        f32x4 a2 = *(const f32x4*)&hsd[2][c];
        f32x4 a3 = *(const f32x4*)&hsd[3][c];
        g0 = fmaf(a0.x,w0, fmaf(a0.y,w1, fmaf(a0.z,w2_, fmaf(a0.w,w3, g0))));
        g1 = fmaf(a1.x,w0, fmaf(a1.y,w1, fmaf(a1.z,w2_, fmaf(a1.w,w3, g1))));
        g2 = fmaf(a2.x,w0, fmaf(a2.y,w1, fmaf(a2.z,w2_, fmaf(a2.w,w3, g2))));
        g3 = fmaf(a3.x,w0, fmaf(a3.y,w1, fmaf(a3.z,w2_, fmaf(a3.w,w3, g3))));
      }
      u.gp[0][p4_g] = g0;
      u.gp[1][p4_g] = g1;
      u.gp[2][p4_g] = g2;
      u.gp[3][p4_g] = g3;
    }
    __syncthreads();

    // ---------- P5: pointwise LSTM + output
    {
      float s0 = u.gp[o_b][o_j]       + bl0;
      float s1 = u.gp[o_b][o_j + 128] + bl1;
      float s2 = u.gp[o_b][o_j + 256] + bl2;
      float s3 = u.gp[o_b][o_j + 384] + bl3;
      float ig = fast_sig(s0), fg = fast_sig(s1);
      float gg = fast_tanh(s2), og = fast_sig(s3);
      float cn = fmaf(fg, csd[o_b][o_j], ig*gg);
      float hn = og * fast_tanh(cn);
      csd[o_b][o_j] = cn;
      hsd[o_b][o_j] = hn;
      out[(b0+o_b)*16384 + (long)t*128 + o_j] = hn;
    }
    __syncthreads();
  }
}

extern "C" void kernel_launch(void* const* d_in, const int* in_sizes, int n_in,
                              void* d_out, int out_size, void* d_ws, size_t ws_size,
                              hipStream_t stream) {
  const float* X   = (const float*)d_in[0];
  const float* Wat = (const float*)d_in[1];
  const float* b1  = (const float*)d_in[2];
  const float* w2  = (const float*)d_in[3];
  const float* Wih = (const float*)d_in[5];
  const float* Whh = (const float*)d_in[6];
  const float* bih = (const float*)d_in[7];
  const float* bhh = (const float*)d_in[8];
  float* out  = (float*)d_out;
  float* Wt   = (float*)d_ws;            // 16384
  float* W1T  = Wt + 16384;              // 32768
  float* WcT  = W1T + 32768;             // 98304
  float* prex = WcT + 98304;             // 16777216

  k0_wt  <<<64,  256, 0, stream>>>(Wat, Wt);
  k0_w1t <<<128, 256, 0, stream>>>(Wat, W1T);
  k0_wct <<<384, 256, 0, stream>>>(Wih, Whh, WcT);
  k1_prex<<<2048,256, 0, stream>>>(X, Wt, b1, prex);
  k2_lstm<<<512, 512, 0, stream>>>(X, W1T, WcT, w2, bih, bhh, prex, out);
}